// Round 12
// baseline (2292.365 us; speedup 1.0000x reference)
//
#include <hip/hip_runtime.h>
#include <math.h>

#define DEV __device__ __forceinline__

// ---- problem constants ----
#define PP    256          // pairs
#define BIMG  16
#define HB    712          // bilinear dim
#define KBIL  (712*712)    // 506944
#define KSTEPS (KBIL/32)   // 15842
#define DRELC 1936
#define BILSPLIT 61
#define BILCH   260        // ceil(15842/61); grid 12*2*61=1464

// ---- d_out layout (floats) ----
#define SZ_ACT    (16*157)
#define OFF_ACT   0
#define OFF_POOLED (SZ_ACT)
#define SZ_POOLED (16*1936)
#define OFF_MEM   (OFF_POOLED + SZ_POOLED)
#define SZ_MEM    (24*16*1936)
#define OFF_MASK  (OFF_MEM + SZ_MEM)
#define SZ_MASK   (16*24)

// ---- ws layout (floats) ----
#define OFF_S     0
#define OFF_O     (OFF_S + 256*712)
#define OFF_Z1    (OFF_O + 256*712)
#define OFF_BIL   (OFF_Z1 + 256*712)
#define OFF_REL   (OFF_BIL + 256*712)
#define OFF_UBUF  (OFF_REL + 256*1936)
#define OFF_XP    (OFF_UBUF + 12544*256)
#define OFF_SHARED (OFF_XP + 256*128*49)
#define OFF_X1    OFF_SHARED                       // 256*128*196 floats
#define OFF_PVR   OFF_SHARED                       // 32*256*512 = 4.19M <= 6.42M
// pbil (61*256*712 = 11.12M floats) aliases ubuf+xp+shared (11.24M), all dead
// by the time the bilinear runs. lin/proj partials (0.73M) alias OFF_UBUF too,
// consumed by their reduce before pbil is written (stream-ordered).
#define OFF_PBIL  OFF_UBUF
#define OFF_PLIN  OFF_UBUF
#define OFF_PPROJ OFF_UBUF
#define SZ_SHARED (256*128*196)                    // max(x1, pvr)
#define OFF_INTS  (OFF_SHARED + SZ_SHARED)

typedef __bf16 bf16x8 __attribute__((ext_vector_type(8)));
typedef float  f32x4  __attribute__((ext_vector_type(4)));

// ============================================================
// Bilinear via SINGLE-bf16 MFMA (1-term), depth-2 pipeline.
// Round-6 skeleton (proven non-spilling). Per z-step:
//   8 MFMA/wave (was 24), ~60 VALU (was ~110), LDS halved.
// Numerics: per-product rel err 2^-9 -> output abs err ~2e-3
// (vs demonstrated >=0.031 tolerance slack).
// ============================================================
struct Araw { float s0, s1; float4 o00, o01, o10, o11; };

__global__ __launch_bounds__(256, 4) void bil_mfma_k(
    const float* __restrict__ s, const float* __restrict__ o,
    const float* __restrict__ W, float* __restrict__ part) {
  __shared__ __align__(16) __bf16 Wsh[2][64*40];   // [buf][row*40+k], 10.2 KB

  const int tid = threadIdx.x;
  const int C0 = blockIdx.x * 64;
  const int rowBase = blockIdx.y * 128;
  const int z0 = blockIdx.z * BILCH;
  const int zEnd = min(KSTEPS, z0 + BILCH);

  const int srow = tid >> 2;
  const int koff = (tid & 3) * 8;
  const int sc = C0 + srow;
  const float* wbase = (sc < 712) ? (W + (size_t)sc * KBIL + koff) : (const float*)0;

  const int wv = tid >> 6, lane = tid & 63;
  const int lr = lane & 15, lg = lane >> 4;
  const int n0 = rowBase + wv * 32 + lr;

  f32x4 acc[2][4];
  #pragma unroll
  for (int a = 0; a < 2; a++)
    #pragma unroll
    for (int b = 0; b < 4; b++) { acc[a][b][0]=0.f; acc[a][b][1]=0.f; acc[a][b][2]=0.f; acc[a][b][3]=0.f; }

  auto wload = [&](int z, float4& va, float4& vb) {
    if (wbase) {
      const float* p = wbase + (size_t)z * 32;
      va = *(const float4*)p;
      vb = *(const float4*)(p + 4);
    } else {
      va = make_float4(0.f,0.f,0.f,0.f);
      vb = make_float4(0.f,0.f,0.f,0.f);
    }
  };
  auto wstore = [&](int buf, const float4& va, const float4& vb) {
    float t[8] = {va.x, va.y, va.z, va.w, vb.x, vb.y, vb.z, vb.w};
    bf16x8 hi;
    #pragma unroll
    for (int i = 0; i < 8; i++) hi[i] = (__bf16)t[i];
    *(bf16x8*)&Wsh[buf][srow*40 + koff] = hi;
  };
  auto aload = [&](int z, Araw& a) {
    const int kk = z * 32 + lg * 8;
    const int h = kk / 712;
    const int t = kk - h * 712;
    const float* or0 = o + n0 * 712 + t;
    const float* or1 = o + (n0 + 16) * 712 + t;
    a.s0 = s[n0 * 712 + h];
    a.s1 = s[(n0 + 16) * 712 + h];
    a.o00 = *(const float4*)or0; a.o01 = *(const float4*)(or0 + 4);
    a.o10 = *(const float4*)or1; a.o11 = *(const float4*)(or1 + 4);
  };
  auto amake = [&](const Araw& a, bf16x8 (&ahi)[2]) {
    float p0[8] = {a.o00.x,a.o00.y,a.o00.z,a.o00.w, a.o01.x,a.o01.y,a.o01.z,a.o01.w};
    float p1[8] = {a.o10.x,a.o10.y,a.o10.z,a.o10.w, a.o11.x,a.o11.y,a.o11.z,a.o11.w};
    #pragma unroll
    for (int i = 0; i < 8; i++) {
      ahi[0][i] = (__bf16)(a.s0 * p0[i]);
      ahi[1][i] = (__bf16)(a.s1 * p1[i]);
    }
  };
  auto domfma = [&](int buf, bf16x8 (&ahi)[2]) {
    #pragma unroll
    for (int cf = 0; cf < 4; cf++) {
      bf16x8 bhi = *(bf16x8*)&Wsh[buf][(cf*16 + lr)*40 + lg*8];
      #pragma unroll
      for (int rf = 0; rf < 2; rf++) {
        acc[rf][cf] = __builtin_amdgcn_mfma_f32_16x16x32_bf16(ahi[rf], bhi, acc[rf][cf], 0, 0, 0);
      }
    }
  };

  Araw A0, A1;
  {
    float4 pa, pb;
    wload(z0, pa, pb);
    aload(z0, A0);
    wstore(0, pa, pb);
  }
  float4 s0a, s0b, s1a, s1b;
  wload(min(z0 + 1, zEnd - 1), s0a, s0b);
  wload(min(z0 + 2, zEnd - 1), s1a, s1b);
  __syncthreads();

  int z = z0;
  for (; z + 1 < zEnd; z += 2) {
    aload(z + 1, A1);
    {
      bf16x8 ahi[2];
      amake(A0, ahi);
      domfma(0, ahi);
    }
    wstore(1, s0a, s0b);
    wload(min(z + 3, zEnd - 1), s0a, s0b);
    __syncthreads();
    aload(min(z + 2, zEnd - 1), A0);
    {
      bf16x8 ahi[2];
      amake(A1, ahi);
      domfma(1, ahi);
    }
    wstore(0, s1a, s1b);
    wload(min(z + 4, zEnd - 1), s1a, s1b);
    __syncthreads();
  }
  if (z < zEnd) {
    bf16x8 ahi[2];
    amake(A0, ahi);
    domfma(0, ahi);
  }

  const int bz = blockIdx.z;
  #pragma unroll
  for (int rf = 0; rf < 2; rf++) {
    #pragma unroll
    for (int cf = 0; cf < 4; cf++) {
      const int c = C0 + cf*16 + lr;
      if (c >= 712) continue;
      #pragma unroll
      for (int i = 0; i < 4; i++) {
        const int n = rowBase + wv*32 + rf*16 + lg*4 + i;
        part[((size_t)bz*256 + n)*712 + c] = acc[rf][cf][i];
      }
    }
  }
}

struct GP {
  const float* A; const float* A2; const float* B; const float* bias;
  float* C;
  const int* gidx; int goff;
  int M, N, K;
  int ldc, coff;
  int kChunk;
  const float* bn_g; const float* bn_b; const float* bn_m; const float* bn_v;
  const float* B2; const float* bias2; float* C2;   // mode 0 pair-merge
};

// modes:
// 0: A gathered via gidx col=blockIdx.z; B/bias/C selected by blockIdx.z
// 2: plain A (ubuf rows), plain B (vr_w)        epi: partial C[z][M][N]
// 3: A = concat(s,o)                            epi: partial C[z][M][N]
// 4: A = relu(concat(z1,bil))                   epi: partial C[z][M][N]
// 5: A = union_feat gather [(n,q)][ic]          epi: +bias -> ubuf[n][oc][q]
// 6: A = im2col(xp) 3x3 pad1                    epi: bn2(relu(+bias)) += ubuf[n][oc][q]
// 8: plain A                                    epi: sigmoid(+bias) -> C

template<int MODE>
DEV float loadA(const GP& p, int r, int k) {
  if (MODE == 0) { int fr = p.gidx[2*r + (int)blockIdx.z]; return p.A[fr*2048 + k]; }
  if (MODE == 2 || MODE == 8) return p.A[r*p.K + k];
  if (MODE == 3) return (k < 712) ? p.A[r*712 + k] : p.A2[r*712 + (k-712)];
  if (MODE == 4) { float v = (k < 712) ? p.A[r*712 + k] : p.A2[r*712 + (k-712)];
                   return fmaxf(v, 0.f); }
  if (MODE == 5) { int n = r/49, q = r - n*49; return p.A[(n*1024 + k)*49 + q]; }
  if (MODE == 6) {
    int n = r/49, q = r - n*49; int py = q/7, px = q - py*7;
    int ic = k/9, k9 = k - ic*9; int dy = k9/3, dx = k9 - dy*3;
    int iy = py + dy - 1, ix = px + dx - 1;
    if ((unsigned)iy >= 7u || (unsigned)ix >= 7u) return 0.f;
    return p.A[(n*128 + ic)*49 + iy*7 + ix];
  }
  return 0.f;
}

template<int MODE>
DEV float loadB(const GP& p, int c, int k) {
  if (MODE == 0) { const float* Bp = blockIdx.z ? p.B2 : p.B; return Bp[c*p.K + k]; }
  return p.B[c*p.K + k];
}

// ============================================================
// Generic GEMM, bf16-split MFMA (3-term, unchanged from r10/11).
// ============================================================
template<int MODE>
__global__ __launch_bounds__(256) void gemm_k(GP p) {
  __shared__ __align__(16) __bf16 Ash[2][64*44];
  __shared__ __align__(16) __bf16 Bsh[2][64*44];
  const int tid = threadIdx.x;
  const int srow = tid & 63, koff = (tid >> 6) * 8;
  const int col0 = blockIdx.x * 64, row0 = blockIdx.y * 64;
  const int kStart = (MODE == 0) ? 0 : blockIdx.z * p.kChunk;
  const int kEnd = min(p.K, kStart + p.kChunk);
  const int wv = tid >> 6, lane = tid & 63;
  const int lr = lane & 15, lg = lane >> 4;
  const int rh = wv >> 1, ch = wv & 1;

  f32x4 acc[2][2];
  #pragma unroll
  for (int a = 0; a < 2; a++)
    #pragma unroll
    for (int b = 0; b < 2; b++) { acc[a][b][0]=0.f; acc[a][b][1]=0.f; acc[a][b][2]=0.f; acc[a][b][3]=0.f; }

  for (int kb = kStart; kb < kEnd; kb += 32) {
    {
      const int gr = row0 + srow;
      float v[8];
      #pragma unroll
      for (int i = 0; i < 8; i++) {
        const int gk = kb + koff + i;
        v[i] = (gr < p.M && gk < kEnd) ? loadA<MODE>(p, gr, gk) : 0.f;
      }
      bf16x8 hi, lo;
      #pragma unroll
      for (int i = 0; i < 8; i++) {
        __bf16 h = (__bf16)v[i];
        hi[i] = h;
        lo[i] = (__bf16)(v[i] - (float)h);
      }
      *(bf16x8*)&Ash[0][srow*44 + koff] = hi;
      *(bf16x8*)&Ash[1][srow*44 + koff] = lo;
    }
    {
      const int gc = col0 + srow;
      float v[8];
      #pragma unroll
      for (int i = 0; i < 8; i++) {
        const int gk = kb + koff + i;
        v[i] = (gc < p.N && gk < kEnd) ? loadB<MODE>(p, gc, gk) : 0.f;
      }
      bf16x8 hi, lo;
      #pragma unroll
      for (int i = 0; i < 8; i++) {
        __bf16 h = (__bf16)v[i];
        hi[i] = h;
        lo[i] = (__bf16)(v[i] - (float)h);
      }
      *(bf16x8*)&Bsh[0][srow*44 + koff] = hi;
      *(bf16x8*)&Bsh[1][srow*44 + koff] = lo;
    }
    __syncthreads();
    #pragma unroll
    for (int rf = 0; rf < 2; rf++) {
      bf16x8 ahi = *(const bf16x8*)&Ash[0][(rh*32 + rf*16 + lr)*44 + lg*8];
      bf16x8 alo = *(const bf16x8*)&Ash[1][(rh*32 + rf*16 + lr)*44 + lg*8];
      #pragma unroll
      for (int cf = 0; cf < 2; cf++) {
        bf16x8 bhi = *(const bf16x8*)&Bsh[0][(ch*32 + cf*16 + lr)*44 + lg*8];
        bf16x8 blo = *(const bf16x8*)&Bsh[1][(ch*32 + cf*16 + lr)*44 + lg*8];
        acc[rf][cf] = __builtin_amdgcn_mfma_f32_16x16x32_bf16(ahi, bhi, acc[rf][cf], 0, 0, 0);
        acc[rf][cf] = __builtin_amdgcn_mfma_f32_16x16x32_bf16(ahi, blo, acc[rf][cf], 0, 0, 0);
        acc[rf][cf] = __builtin_amdgcn_mfma_f32_16x16x32_bf16(alo, bhi, acc[rf][cf], 0, 0, 0);
      }
    }
    __syncthreads();
  }

  // ---- epilogue (D: col=lane&15, row=(lane>>4)*4+i) ----
  #pragma unroll
  for (int rf = 0; rf < 2; rf++) {
    #pragma unroll
    for (int cf = 0; cf < 2; cf++) {
      const int c = col0 + ch*32 + cf*16 + lr;
      if (c >= p.N) continue;
      #pragma unroll
      for (int i = 0; i < 4; i++) {
        const int r = row0 + rh*32 + rf*16 + lg*4 + i;
        if (r >= p.M) continue;
        float v = acc[rf][cf][i];
        if (MODE == 2 || MODE == 3 || MODE == 4) {
          p.C[(size_t)blockIdx.z * p.M * p.N + (size_t)r * p.N + c] = v;
        } else if (MODE == 5) {
          int n = r/49, q = r - n*49;
          p.C[n*12544 + c*49 + q] = v + p.bias[c];
        } else if (MODE == 6) {
          int n = r/49, q = r - n*49;
          float sc = p.bn_g[c] / sqrtf(p.bn_v[c] + 1e-5f);
          float sh = p.bn_b[c] - p.bn_m[c]*sc;
          float t2 = fmaxf(v + p.bias[c], 0.f)*sc + sh;
          p.C[n*12544 + c*49 + q] += t2;
        } else if (MODE == 8) {
          float t2 = v + p.bias[c];
          p.C[r*p.ldc + p.coff + c] = 1.f/(1.f + expf(-t2));
        } else {  // MODE 0: pair-merged subj/obj
          const float* bb = blockIdx.z ? p.bias2 : p.bias;
          float* Cp = blockIdx.z ? p.C2 : p.C;
          Cp[r*p.ldc + p.coff + c] = v + bb[c];
        }
      }
    }
  }
}

__global__ __launch_bounds__(256) void reduce_k(const float* __restrict__ part,
    const float* __restrict__ bias, float* __restrict__ out,
    int S, int MN, int N, int ldc, int coff) {
  int i = blockIdx.x*256 + threadIdx.x;
  if (i >= MN) return;
  float s = 0.f;
  for (int z = 0; z < S; z++) s += part[(size_t)z*MN + i];
  int r = i / N, c = i - r*N;
  out[r*ldc + coff + c] = s + bias[c];
}

__global__ __launch_bounds__(256) void emb_k(const int* __restrict__ pi,
    const int* __restrict__ labels, const float* __restrict__ e1,
    const float* __restrict__ e2, float* __restrict__ s, float* __restrict__ o) {
  int i = blockIdx.x*256 + threadIdx.x;
  if (i >= 2*256*200) return;
  int which = i / (256*200); int rest = i - which*(256*200);
  int n = rest / 200; int j = rest - n*200;
  int lab = labels[pi[2*n + which]];
  float v = which ? e2[lab*200 + j] : e1[lab*200 + j];
  (which ? o : s)[n*712 + 512 + j] = v;
}

__global__ __launch_bounds__(256) void conv1_k(const float* __restrict__ in,
    const float* __restrict__ w, const float* __restrict__ bias,
    const float* __restrict__ g, const float* __restrict__ bt,
    const float* __restrict__ m, const float* __restrict__ vv,
    float* __restrict__ out) {
  int idx = blockIdx.x*256 + threadIdx.x;
  if (idx >= 256*128*14) return;
  int oy = idx % 14; int t = idx / 14; int c = t & 127; int n = t >> 7;
  float acc[14];
  float b0 = bias[c];
  #pragma unroll
  for (int ox = 0; ox < 14; ox++) acc[ox] = b0;
  for (int ci = 0; ci < 2; ci++) {
    #pragma unroll
    for (int ky = 0; ky < 7; ky++) {
      int iy = oy*2 - 3 + ky;
      if ((unsigned)iy >= 27u) continue;
      const float* ir = in + ((n*2 + ci)*27 + iy)*27;
      const float* wr = w + ((c*2 + ci)*7 + ky)*7;
      float iv[27];
      #pragma unroll
      for (int x = 0; x < 27; x++) iv[x] = ir[x];
      float wk[7];
      #pragma unroll
      for (int kx = 0; kx < 7; kx++) wk[kx] = wr[kx];
      #pragma unroll
      for (int kx = 0; kx < 7; kx++)
        #pragma unroll
        for (int ox = 0; ox < 14; ox++) {
          int ix = ox*2 - 3 + kx;
          if (ix >= 0 && ix < 27) acc[ox] += iv[ix]*wk[kx];
        }
    }
  }
  float sc = g[c] / sqrtf(vv[c] + 1e-5f);
  float sh = bt[c] - m[c]*sc;
  float* orow = out + ((n*128 + c)*14 + oy)*14;
  #pragma unroll
  for (int ox = 0; ox < 14; ox++) orow[ox] = fmaxf(acc[ox], 0.f)*sc + sh;
}

__global__ __launch_bounds__(256) void pool_k(const float* __restrict__ x1,
                                              float* __restrict__ xp) {
  int idx = blockIdx.x*256 + threadIdx.x;
  if (idx >= 256*128*49) return;
  int px = idx % 7; int t = idx / 7; int py = t % 7; t /= 7;
  int c = t & 127; int n = t >> 7;
  float mx = -INFINITY;
  for (int dy = 0; dy < 3; dy++) {
    int y = py*2 - 1 + dy;
    if ((unsigned)y >= 14u) continue;
    for (int dx = 0; dx < 3; dx++) {
      int x = px*2 - 1 + dx;
      if ((unsigned)x >= 14u) continue;
      mx = fmaxf(mx, x1[((n*128 + c)*14 + y)*14 + x]);
    }
  }
  xp[((n*128 + c)*7 + py)*7 + px] = mx;
}

__global__ __launch_bounds__(256) void seg_k(const int* __restrict__ im,
    int* __restrict__ counts, int* __restrict__ starts, int* __restrict__ pos) {
  __shared__ int c[16], s[16];
  int tid = threadIdx.x;
  if (tid < 16) c[tid] = 0;
  __syncthreads();
  atomicAdd(&c[im[tid]], 1);
  __syncthreads();
  if (tid == 0) { int run = 0; for (int b = 0; b < 16; b++) { s[b] = run; run += c[b]; } }
  __syncthreads();
  if (tid < 16) { counts[tid] = c[tid]; starts[tid] = s[tid]; }
  pos[tid] = tid - s[im[tid]];
}

__global__ __launch_bounds__(256) void zeromask_k(float* __restrict__ out,
                                                  const int* __restrict__ counts) {
  int i = blockIdx.x*256 + threadIdx.x;
  if (i < SZ_MEM) { out[OFF_MEM + i] = 0.f; return; }
  int j = i - SZ_MEM;
  if (j < SZ_MASK) {
    int b = j / 24, l = j - b*24;
    out[OFF_MASK + j] = (l >= counts[b]) ? 1.f : 0.f;
  }
}

__global__ __launch_bounds__(256) void scatter_k(const float* __restrict__ rel,
    const int* __restrict__ pos, const int* __restrict__ im, float* __restrict__ out) {
  int n = blockIdx.x;
  int l = pos[n], b = im[n];
  float* dst = out + OFF_MEM + ((size_t)l*16 + b)*1936;
  const float* src = rel + (size_t)n*1936;
  for (int d = threadIdx.x; d < 1936; d += 256) dst[d] = src[d];
}

__global__ __launch_bounds__(256) void pooled_k(const float* __restrict__ rel,
    const int* __restrict__ starts, const int* __restrict__ counts,
    float* __restrict__ out) {
  int b = blockIdx.y;
  int d = blockIdx.x*256 + threadIdx.x;
  if (d >= 1936) return;
  int st = starts[b], ct = counts[b];
  float mx = -INFINITY;
  for (int i = 0; i < ct; i++) mx = fmaxf(mx, rel[(size_t)(st + i)*1936 + d]);
  out[OFF_POOLED + b*1936 + d] = mx;
}

extern "C" void kernel_launch(void* const* d_in, const int* in_sizes, int n_in,
                              void* d_out, int out_size, void* d_ws, size_t ws_size,
                              hipStream_t stream) {
  const float* features   = (const float*)d_in[0];
  const int*   pair_idx   = (const int*)d_in[1];
  const int*   im_idx     = (const int*)d_in[2];
  const int*   labels     = (const int*)d_in[3];
  const float* union_feat = (const float*)d_in[4];
  const float* spatial    = (const float*)d_in[5];
  const float* w_union    = (const float*)d_in[6];
  const float* b_union    = (const float*)d_in[7];
  const float* conv1_w    = (const float*)d_in[8];
  const float* conv1_b    = (const float*)d_in[9];
  const float* bn1_g      = (const float*)d_in[10];
  const float* bn1_b      = (const float*)d_in[11];
  const float* bn1_m      = (const float*)d_in[12];
  const float* bn1_v      = (const float*)d_in[13];
  const float* conv2_w    = (const float*)d_in[14];
  const float* conv2_b    = (const float*)d_in[15];
  const float* bn2_g      = (const float*)d_in[16];
  const float* bn2_b      = (const float*)d_in[17];
  const float* bn2_m      = (const float*)d_in[18];
  const float* bn2_v      = (const float*)d_in[19];
  const float* subj_w     = (const float*)d_in[20];
  const float* subj_b     = (const float*)d_in[21];
  const float* obj_w      = (const float*)d_in[22];
  const float* obj_b      = (const float*)d_in[23];
  const float* vr_w       = (const float*)d_in[24];
  const float* vr_b       = (const float*)d_in[25];
  const float* emb1       = (const float*)d_in[26];
  const float* emb2       = (const float*)d_in[27];
  const float* bil_w      = (const float*)d_in[28];
  const float* bil_b      = (const float*)d_in[29];
  const float* lin_w      = (const float*)d_in[30];
  const float* lin_b      = (const float*)d_in[31];
  const float* proj_w     = (const float*)d_in[32];
  const float* proj_b     = (const float*)d_in[33];
  const float* ac_w       = (const float*)d_in[34];
  const float* ac_b       = (const float*)d_in[35];

  float* ws = (float*)d_ws;
  float* s_mat  = ws + OFF_S;
  float* o_mat  = ws + OFF_O;
  float* z1     = ws + OFF_Z1;
  float* bilbuf = ws + OFF_BIL;
  float* rel    = ws + OFF_REL;
  float* ubuf   = ws + OFF_UBUF;   // layout [n][oc][q] = [256][256][49]
  float* x1     = ws + OFF_X1;
  float* xp     = ws + OFF_XP;
  float* pvr    = ws + OFF_PVR;
  float* pbil   = ws + OFF_PBIL;
  float* plin   = ws + OFF_PLIN;
  float* pproj  = ws + OFF_PPROJ;
  int*   ints   = (int*)(ws + OFF_INTS);
  int* counts = ints; int* starts = ints + 16; int* pos = ints + 32;
  float* out = (float*)d_out;

  dim3 blk(256);

  // subj + obj linears in ONE dispatch (blockIdx.z selects weights/output)
  {
    GP g{}; g.A = features; g.gidx = pair_idx;
    g.B = subj_w;  g.bias = subj_b;  g.C = s_mat;
    g.B2 = obj_w;  g.bias2 = obj_b;  g.C2 = o_mat;
    g.M = 256; g.N = 512; g.K = 2048; g.ldc = 712; g.coff = 0; g.kChunk = 2048;
    gemm_k<0><<<dim3(8,4,2), blk, 0, stream>>>(g);
  }
  // embedding concat -> cols [512,712)
  emb_k<<<dim3(400), blk, 0, stream>>>(pair_idx, labels, emb1, emb2, s_mat, o_mat);

  // union 1x1 conv as GEMM -> ubuf[n][oc][q] (scatter epilogue)
  {
    GP g{}; g.A = union_feat; g.B = w_union; g.bias = b_union; g.C = ubuf;
    g.M = 12544; g.N = 256; g.K = 1024; g.kChunk = 1024;
    gemm_k<5><<<dim3(4,196,1), blk, 0, stream>>>(g);
  }

  // conv1 + relu + bn1 -> x1 ; maxpool -> xp
  conv1_k<<<dim3(1792), blk, 0, stream>>>(spatial, conv1_w, conv1_b,
                                          bn1_g, bn1_b, bn1_m, bn1_v, x1);
  pool_k<<<dim3(6272), blk, 0, stream>>>(x1, xp);

  // conv2 (implicit GEMM) + relu + bn2, accumulated into ubuf[n][oc][q]
  {
    GP g{}; g.A = xp; g.B = conv2_w; g.bias = conv2_b; g.C = ubuf;
    g.M = 12544; g.N = 256; g.K = 1152; g.kChunk = 1152;
    g.bn_g = bn2_g; g.bn_b = bn2_b; g.bn_m = bn2_m; g.bn_v = bn2_v;
    gemm_k<6><<<dim3(4,196,1), blk, 0, stream>>>(g);
  }

  // vr linear: split-K 32 -> partials -> rel[:,1424:1936]
  {
    GP g{}; g.A = ubuf; g.B = vr_w; g.C = pvr;
    g.M = 256; g.N = 512; g.K = 12544; g.kChunk = 392;
    gemm_k<2><<<dim3(8,4,32), blk, 0, stream>>>(g);
    reduce_k<<<dim3(512), blk, 0, stream>>>(pvr, vr_b, rel, 32, 256*512, 512, 1936, 1424);
  }

  // lin: concat(s,o) @ lin_w^T, split-K 4 -> partials -> z1
  {
    GP g{}; g.A = s_mat; g.A2 = o_mat; g.B = lin_w; g.C = plin;
    g.M = 256; g.N = 712; g.K = 1424; g.kChunk = 356;
    gemm_k<3><<<dim3(12,4,4), blk, 0, stream>>>(g);
    reduce_k<<<dim3(712), blk, 0, stream>>>(plin, lin_b, z1, 4, 256*712, 712, 712, 0);
  }

  // bilinear: single-bf16 MFMA, depth-2 pipeline, split-K 61 -> partials -> bilbuf
  bil_mfma_k<<<dim3(12, 2, BILSPLIT), dim3(256), 0, stream>>>(s_mat, o_mat, bil_w, pbil);
  reduce_k<<<dim3(712), blk, 0, stream>>>(pbil, bil_b, bilbuf, BILSPLIT, 256*712, 712, 712, 0);

  // proj: relu(concat(z1,bil)) @ proj_w^T, split-K 2 -> partials -> rel[:,0:1424]
  {
    GP g{}; g.A = z1; g.A2 = bilbuf; g.B = proj_w; g.C = pproj;
    g.M = 256; g.N = 1424; g.K = 1424; g.kChunk = 712;
    gemm_k<4><<<dim3(23,4,2), blk, 0, stream>>>(g);
    reduce_k<<<dim3(1424), blk, 0, stream>>>(pproj, proj_b, rel, 2, 256*1424, 1424, 1936, 0);
  }

  // segments, memory zero + mask, scatter, pooled max
  seg_k<<<dim3(1), blk, 0, stream>>>(im_idx, counts, starts, pos);
  zeromask_k<<<dim3((SZ_MEM + SZ_MASK + 255)/256), blk, 0, stream>>>(out, counts);
  scatter_k<<<dim3(256), blk, 0, stream>>>(rel, pos, im_idx, out);
  pooled_k<<<dim3(8,16), blk, 0, stream>>>(rel, starts, counts, out);

  // act = sigmoid(pooled @ ac_w^T + ac_b)
  {
    GP g{}; g.A = out + OFF_POOLED; g.B = ac_w; g.bias = ac_b; g.C = out + OFF_ACT;
    g.M = 16; g.N = 157; g.K = 1936; g.ldc = 157; g.coff = 0; g.kChunk = 1936;
    gemm_k<8><<<dim3(3,1,1), blk, 0, stream>>>(g);
  }
}

// Round 13
// 2282.843 us; speedup vs baseline: 1.0042x; 1.0042x over previous
//
#include <hip/hip_runtime.h>
#include <math.h>

#define DEV __device__ __forceinline__

// ---- problem constants ----
#define PP    256          // pairs
#define BIMG  16
#define HB    712          // bilinear dim
#define KBIL  (712*712)    // 506944
#define KSTEPS (KBIL/32)   // 15842
#define DRELC 1936
#define BILSPLIT 61
#define BILCH   260        // ceil(15842/61); grid 12*2*61=1464

// ---- d_out layout (floats) ----
#define SZ_ACT    (16*157)
#define OFF_ACT   0
#define OFF_POOLED (SZ_ACT)
#define SZ_POOLED (16*1936)
#define OFF_MEM   (OFF_POOLED + SZ_POOLED)
#define SZ_MEM    (24*16*1936)
#define OFF_MASK  (OFF_MEM + SZ_MEM)
#define SZ_MASK   (16*24)

// ---- ws layout (floats) ----
#define OFF_S     0
#define OFF_O     (OFF_S + 256*712)
#define OFF_Z1    (OFF_O + 256*712)
#define OFF_BIL   (OFF_Z1 + 256*712)
#define OFF_REL   (OFF_BIL + 256*712)
#define OFF_UBUF  (OFF_REL + 256*1936)
#define OFF_XP    (OFF_UBUF + 12544*256)
#define OFF_SHARED (OFF_XP + 256*128*49)
#define OFF_X1    OFF_SHARED                       // 256*128*196 floats
#define OFF_PVR   OFF_SHARED                       // 32*256*512 = 4.19M <= 6.42M
// pbil (61*256*712 = 11.12M floats) aliases ubuf+xp+shared (11.24M), all dead
// by the time the bilinear runs. lin/proj partials (0.73M) alias OFF_UBUF too,
// consumed by their reduce before pbil is written (stream-ordered).
#define OFF_PBIL  OFF_UBUF
#define OFF_PLIN  OFF_UBUF
#define OFF_PPROJ OFF_UBUF
#define SZ_SHARED (256*128*196)                    // max(x1, pvr)
#define OFF_INTS  (OFF_SHARED + SZ_SHARED)

typedef __bf16 bf16x8 __attribute__((ext_vector_type(8)));
typedef float  f32x4  __attribute__((ext_vector_type(4)));

// Barrier WITHOUT vmcnt drain: LDS ordering only (lgkmcnt), so global
// prefetch FIFO stays in flight across the barrier. __syncthreads()
// lowers to s_waitcnt vmcnt(0) lgkmcnt(0); s_barrier, which force-
// retires every in-flight W load each step (the suspected convoy).
#define LGKM_BARRIER() asm volatile("s_waitcnt lgkmcnt(0)\n\ts_barrier" ::: "memory")

// ============================================================
// Bilinear via SINGLE-bf16 MFMA (1-term), depth-2 pipeline.
// r12 skeleton; ONLY change: loop barriers are lgkm-only.
// ============================================================
struct Araw { float s0, s1; float4 o00, o01, o10, o11; };

__global__ __launch_bounds__(256, 4) void bil_mfma_k(
    const float* __restrict__ s, const float* __restrict__ o,
    const float* __restrict__ W, float* __restrict__ part) {
  __shared__ __align__(16) __bf16 Wsh[2][64*40];   // [buf][row*40+k], 10.2 KB

  const int tid = threadIdx.x;
  const int C0 = blockIdx.x * 64;
  const int rowBase = blockIdx.y * 128;
  const int z0 = blockIdx.z * BILCH;
  const int zEnd = min(KSTEPS, z0 + BILCH);

  const int srow = tid >> 2;
  const int koff = (tid & 3) * 8;
  const int sc = C0 + srow;
  const float* wbase = (sc < 712) ? (W + (size_t)sc * KBIL + koff) : (const float*)0;

  const int wv = tid >> 6, lane = tid & 63;
  const int lr = lane & 15, lg = lane >> 4;
  const int n0 = rowBase + wv * 32 + lr;

  f32x4 acc[2][4];
  #pragma unroll
  for (int a = 0; a < 2; a++)
    #pragma unroll
    for (int b = 0; b < 4; b++) { acc[a][b][0]=0.f; acc[a][b][1]=0.f; acc[a][b][2]=0.f; acc[a][b][3]=0.f; }

  auto wload = [&](int z, float4& va, float4& vb) {
    if (wbase) {
      const float* p = wbase + (size_t)z * 32;
      va = *(const float4*)p;
      vb = *(const float4*)(p + 4);
    } else {
      va = make_float4(0.f,0.f,0.f,0.f);
      vb = make_float4(0.f,0.f,0.f,0.f);
    }
  };
  auto wstore = [&](int buf, const float4& va, const float4& vb) {
    float t[8] = {va.x, va.y, va.z, va.w, vb.x, vb.y, vb.z, vb.w};
    bf16x8 hi;
    #pragma unroll
    for (int i = 0; i < 8; i++) hi[i] = (__bf16)t[i];
    *(bf16x8*)&Wsh[buf][srow*40 + koff] = hi;
  };
  auto aload = [&](int z, Araw& a) {
    const int kk = z * 32 + lg * 8;
    const int h = kk / 712;
    const int t = kk - h * 712;
    const float* or0 = o + n0 * 712 + t;
    const float* or1 = o + (n0 + 16) * 712 + t;
    a.s0 = s[n0 * 712 + h];
    a.s1 = s[(n0 + 16) * 712 + h];
    a.o00 = *(const float4*)or0; a.o01 = *(const float4*)(or0 + 4);
    a.o10 = *(const float4*)or1; a.o11 = *(const float4*)(or1 + 4);
  };
  auto amake = [&](const Araw& a, bf16x8 (&ahi)[2]) {
    float p0[8] = {a.o00.x,a.o00.y,a.o00.z,a.o00.w, a.o01.x,a.o01.y,a.o01.z,a.o01.w};
    float p1[8] = {a.o10.x,a.o10.y,a.o10.z,a.o10.w, a.o11.x,a.o11.y,a.o11.z,a.o11.w};
    #pragma unroll
    for (int i = 0; i < 8; i++) {
      ahi[0][i] = (__bf16)(a.s0 * p0[i]);
      ahi[1][i] = (__bf16)(a.s1 * p1[i]);
    }
  };
  auto domfma = [&](int buf, bf16x8 (&ahi)[2]) {
    #pragma unroll
    for (int cf = 0; cf < 4; cf++) {
      bf16x8 bhi = *(bf16x8*)&Wsh[buf][(cf*16 + lr)*40 + lg*8];
      #pragma unroll
      for (int rf = 0; rf < 2; rf++) {
        acc[rf][cf] = __builtin_amdgcn_mfma_f32_16x16x32_bf16(ahi[rf], bhi, acc[rf][cf], 0, 0, 0);
      }
    }
  };

  Araw A0, A1;
  {
    float4 pa, pb;
    wload(z0, pa, pb);
    aload(z0, A0);
    wstore(0, pa, pb);
  }
  float4 s0a, s0b, s1a, s1b;
  wload(min(z0 + 1, zEnd - 1), s0a, s0b);
  wload(min(z0 + 2, zEnd - 1), s1a, s1b);
  __syncthreads();

  int z = z0;
  for (; z + 1 < zEnd; z += 2) {
    aload(z + 1, A1);
    {
      bf16x8 ahi[2];
      amake(A0, ahi);
      domfma(0, ahi);
    }
    wstore(1, s0a, s0b);
    wload(min(z + 3, zEnd - 1), s0a, s0b);
    LGKM_BARRIER();
    aload(min(z + 2, zEnd - 1), A0);
    {
      bf16x8 ahi[2];
      amake(A1, ahi);
      domfma(1, ahi);
    }
    wstore(0, s1a, s1b);
    wload(min(z + 4, zEnd - 1), s1a, s1b);
    LGKM_BARRIER();
  }
  if (z < zEnd) {
    bf16x8 ahi[2];
    amake(A0, ahi);
    domfma(0, ahi);
  }

  const int bz = blockIdx.z;
  #pragma unroll
  for (int rf = 0; rf < 2; rf++) {
    #pragma unroll
    for (int cf = 0; cf < 4; cf++) {
      const int c = C0 + cf*16 + lr;
      if (c >= 712) continue;
      #pragma unroll
      for (int i = 0; i < 4; i++) {
        const int n = rowBase + wv*32 + rf*16 + lg*4 + i;
        part[((size_t)bz*256 + n)*712 + c] = acc[rf][cf][i];
      }
    }
  }
}

struct GP {
  const float* A; const float* A2; const float* B; const float* bias;
  float* C;
  const int* gidx; int goff;
  int M, N, K;
  int ldc, coff;
  int kChunk;
  const float* bn_g; const float* bn_b; const float* bn_m; const float* bn_v;
  const float* B2; const float* bias2; float* C2;   // mode 0 pair-merge
};

// modes:
// 0: A gathered via gidx col=blockIdx.z; B/bias/C selected by blockIdx.z
// 2: plain A (ubuf rows), plain B (vr_w)        epi: partial C[z][M][N]
// 3: A = concat(s,o)                            epi: partial C[z][M][N]
// 4: A = relu(concat(z1,bil))                   epi: partial C[z][M][N]
// 5: A = union_feat gather [(n,q)][ic]          epi: +bias -> ubuf[n][oc][q]
// 6: A = im2col(xp) 3x3 pad1                    epi: bn2(relu(+bias)) += ubuf[n][oc][q]
// 8: plain A                                    epi: sigmoid(+bias) -> C

template<int MODE>
DEV float loadA(const GP& p, int r, int k) {
  if (MODE == 0) { int fr = p.gidx[2*r + (int)blockIdx.z]; return p.A[fr*2048 + k]; }
  if (MODE == 2 || MODE == 8) return p.A[r*p.K + k];
  if (MODE == 3) return (k < 712) ? p.A[r*712 + k] : p.A2[r*712 + (k-712)];
  if (MODE == 4) { float v = (k < 712) ? p.A[r*712 + k] : p.A2[r*712 + (k-712)];
                   return fmaxf(v, 0.f); }
  if (MODE == 5) { int n = r/49, q = r - n*49; return p.A[(n*1024 + k)*49 + q]; }
  if (MODE == 6) {
    int n = r/49, q = r - n*49; int py = q/7, px = q - py*7;
    int ic = k/9, k9 = k - ic*9; int dy = k9/3, dx = k9 - dy*3;
    int iy = py + dy - 1, ix = px + dx - 1;
    if ((unsigned)iy >= 7u || (unsigned)ix >= 7u) return 0.f;
    return p.A[(n*128 + ic)*49 + iy*7 + ix];
  }
  return 0.f;
}

template<int MODE>
DEV float loadB(const GP& p, int c, int k) {
  if (MODE == 0) { const float* Bp = blockIdx.z ? p.B2 : p.B; return Bp[c*p.K + k]; }
  return p.B[c*p.K + k];
}

// ============================================================
// Generic GEMM, bf16-split MFMA (3-term, unchanged from r10/11).
// ============================================================
template<int MODE>
__global__ __launch_bounds__(256) void gemm_k(GP p) {
  __shared__ __align__(16) __bf16 Ash[2][64*44];
  __shared__ __align__(16) __bf16 Bsh[2][64*44];
  const int tid = threadIdx.x;
  const int srow = tid & 63, koff = (tid >> 6) * 8;
  const int col0 = blockIdx.x * 64, row0 = blockIdx.y * 64;
  const int kStart = (MODE == 0) ? 0 : blockIdx.z * p.kChunk;
  const int kEnd = min(p.K, kStart + p.kChunk);
  const int wv = tid >> 6, lane = tid & 63;
  const int lr = lane & 15, lg = lane >> 4;
  const int rh = wv >> 1, ch = wv & 1;

  f32x4 acc[2][2];
  #pragma unroll
  for (int a = 0; a < 2; a++)
    #pragma unroll
    for (int b = 0; b < 2; b++) { acc[a][b][0]=0.f; acc[a][b][1]=0.f; acc[a][b][2]=0.f; acc[a][b][3]=0.f; }

  for (int kb = kStart; kb < kEnd; kb += 32) {
    {
      const int gr = row0 + srow;
      float v[8];
      #pragma unroll
      for (int i = 0; i < 8; i++) {
        const int gk = kb + koff + i;
        v[i] = (gr < p.M && gk < kEnd) ? loadA<MODE>(p, gr, gk) : 0.f;
      }
      bf16x8 hi, lo;
      #pragma unroll
      for (int i = 0; i < 8; i++) {
        __bf16 h = (__bf16)v[i];
        hi[i] = h;
        lo[i] = (__bf16)(v[i] - (float)h);
      }
      *(bf16x8*)&Ash[0][srow*44 + koff] = hi;
      *(bf16x8*)&Ash[1][srow*44 + koff] = lo;
    }
    {
      const int gc = col0 + srow;
      float v[8];
      #pragma unroll
      for (int i = 0; i < 8; i++) {
        const int gk = kb + koff + i;
        v[i] = (gc < p.N && gk < kEnd) ? loadB<MODE>(p, gc, gk) : 0.f;
      }
      bf16x8 hi, lo;
      #pragma unroll
      for (int i = 0; i < 8; i++) {
        __bf16 h = (__bf16)v[i];
        hi[i] = h;
        lo[i] = (__bf16)(v[i] - (float)h);
      }
      *(bf16x8*)&Bsh[0][srow*44 + koff] = hi;
      *(bf16x8*)&Bsh[1][srow*44 + koff] = lo;
    }
    __syncthreads();
    #pragma unroll
    for (int rf = 0; rf < 2; rf++) {
      bf16x8 ahi = *(const bf16x8*)&Ash[0][(rh*32 + rf*16 + lr)*44 + lg*8];
      bf16x8 alo = *(const bf16x8*)&Ash[1][(rh*32 + rf*16 + lr)*44 + lg*8];
      #pragma unroll
      for (int cf = 0; cf < 2; cf++) {
        bf16x8 bhi = *(const bf16x8*)&Bsh[0][(ch*32 + cf*16 + lr)*44 + lg*8];
        bf16x8 blo = *(const bf16x8*)&Bsh[1][(ch*32 + cf*16 + lr)*44 + lg*8];
        acc[rf][cf] = __builtin_amdgcn_mfma_f32_16x16x32_bf16(ahi, bhi, acc[rf][cf], 0, 0, 0);
        acc[rf][cf] = __builtin_amdgcn_mfma_f32_16x16x32_bf16(ahi, blo, acc[rf][cf], 0, 0, 0);
        acc[rf][cf] = __builtin_amdgcn_mfma_f32_16x16x32_bf16(alo, bhi, acc[rf][cf], 0, 0, 0);
      }
    }
    __syncthreads();
  }

  // ---- epilogue (D: col=lane&15, row=(lane>>4)*4+i) ----
  #pragma unroll
  for (int rf = 0; rf < 2; rf++) {
    #pragma unroll
    for (int cf = 0; cf < 2; cf++) {
      const int c = col0 + ch*32 + cf*16 + lr;
      if (c >= p.N) continue;
      #pragma unroll
      for (int i = 0; i < 4; i++) {
        const int r = row0 + rh*32 + rf*16 + lg*4 + i;
        if (r >= p.M) continue;
        float v = acc[rf][cf][i];
        if (MODE == 2 || MODE == 3 || MODE == 4) {
          p.C[(size_t)blockIdx.z * p.M * p.N + (size_t)r * p.N + c] = v;
        } else if (MODE == 5) {
          int n = r/49, q = r - n*49;
          p.C[n*12544 + c*49 + q] = v + p.bias[c];
        } else if (MODE == 6) {
          int n = r/49, q = r - n*49;
          float sc = p.bn_g[c] / sqrtf(p.bn_v[c] + 1e-5f);
          float sh = p.bn_b[c] - p.bn_m[c]*sc;
          float t2 = fmaxf(v + p.bias[c], 0.f)*sc + sh;
          p.C[n*12544 + c*49 + q] += t2;
        } else if (MODE == 8) {
          float t2 = v + p.bias[c];
          p.C[r*p.ldc + p.coff + c] = 1.f/(1.f + expf(-t2));
        } else {  // MODE 0: pair-merged subj/obj
          const float* bb = blockIdx.z ? p.bias2 : p.bias;
          float* Cp = blockIdx.z ? p.C2 : p.C;
          Cp[r*p.ldc + p.coff + c] = v + bb[c];
        }
      }
    }
  }
}

__global__ __launch_bounds__(256) void reduce_k(const float* __restrict__ part,
    const float* __restrict__ bias, float* __restrict__ out,
    int S, int MN, int N, int ldc, int coff) {
  int i = blockIdx.x*256 + threadIdx.x;
  if (i >= MN) return;
  float s = 0.f;
  for (int z = 0; z < S; z++) s += part[(size_t)z*MN + i];
  int r = i / N, c = i - r*N;
  out[r*ldc + coff + c] = s + bias[c];
}

__global__ __launch_bounds__(256) void emb_k(const int* __restrict__ pi,
    const int* __restrict__ labels, const float* __restrict__ e1,
    const float* __restrict__ e2, float* __restrict__ s, float* __restrict__ o) {
  int i = blockIdx.x*256 + threadIdx.x;
  if (i >= 2*256*200) return;
  int which = i / (256*200); int rest = i - which*(256*200);
  int n = rest / 200; int j = rest - n*200;
  int lab = labels[pi[2*n + which]];
  float v = which ? e2[lab*200 + j] : e1[lab*200 + j];
  (which ? o : s)[n*712 + 512 + j] = v;
}

__global__ __launch_bounds__(256) void conv1_k(const float* __restrict__ in,
    const float* __restrict__ w, const float* __restrict__ bias,
    const float* __restrict__ g, const float* __restrict__ bt,
    const float* __restrict__ m, const float* __restrict__ vv,
    float* __restrict__ out) {
  int idx = blockIdx.x*256 + threadIdx.x;
  if (idx >= 256*128*14) return;
  int oy = idx % 14; int t = idx / 14; int c = t & 127; int n = t >> 7;
  float acc[14];
  float b0 = bias[c];
  #pragma unroll
  for (int ox = 0; ox < 14; ox++) acc[ox] = b0;
  for (int ci = 0; ci < 2; ci++) {
    #pragma unroll
    for (int ky = 0; ky < 7; ky++) {
      int iy = oy*2 - 3 + ky;
      if ((unsigned)iy >= 27u) continue;
      const float* ir = in + ((n*2 + ci)*27 + iy)*27;
      const float* wr = w + ((c*2 + ci)*7 + ky)*7;
      float iv[27];
      #pragma unroll
      for (int x = 0; x < 27; x++) iv[x] = ir[x];
      float wk[7];
      #pragma unroll
      for (int kx = 0; kx < 7; kx++) wk[kx] = wr[kx];
      #pragma unroll
      for (int kx = 0; kx < 7; kx++)
        #pragma unroll
        for (int ox = 0; ox < 14; ox++) {
          int ix = ox*2 - 3 + kx;
          if (ix >= 0 && ix < 27) acc[ox] += iv[ix]*wk[kx];
        }
    }
  }
  float sc = g[c] / sqrtf(vv[c] + 1e-5f);
  float sh = bt[c] - m[c]*sc;
  float* orow = out + ((n*128 + c)*14 + oy)*14;
  #pragma unroll
  for (int ox = 0; ox < 14; ox++) orow[ox] = fmaxf(acc[ox], 0.f)*sc + sh;
}

__global__ __launch_bounds__(256) void pool_k(const float* __restrict__ x1,
                                              float* __restrict__ xp) {
  int idx = blockIdx.x*256 + threadIdx.x;
  if (idx >= 256*128*49) return;
  int px = idx % 7; int t = idx / 7; int py = t % 7; t /= 7;
  int c = t & 127; int n = t >> 7;
  float mx = -INFINITY;
  for (int dy = 0; dy < 3; dy++) {
    int y = py*2 - 1 + dy;
    if ((unsigned)y >= 14u) continue;
    for (int dx = 0; dx < 3; dx++) {
      int x = px*2 - 1 + dx;
      if ((unsigned)x >= 14u) continue;
      mx = fmaxf(mx, x1[((n*128 + c)*14 + y)*14 + x]);
    }
  }
  xp[((n*128 + c)*7 + py)*7 + px] = mx;
}

__global__ __launch_bounds__(256) void seg_k(const int* __restrict__ im,
    int* __restrict__ counts, int* __restrict__ starts, int* __restrict__ pos) {
  __shared__ int c[16], s[16];
  int tid = threadIdx.x;
  if (tid < 16) c[tid] = 0;
  __syncthreads();
  atomicAdd(&c[im[tid]], 1);
  __syncthreads();
  if (tid == 0) { int run = 0; for (int b = 0; b < 16; b++) { s[b] = run; run += c[b]; } }
  __syncthreads();
  if (tid < 16) { counts[tid] = c[tid]; starts[tid] = s[tid]; }
  pos[tid] = tid - s[im[tid]];
}

__global__ __launch_bounds__(256) void zeromask_k(float* __restrict__ out,
                                                  const int* __restrict__ counts) {
  int i = blockIdx.x*256 + threadIdx.x;
  if (i < SZ_MEM) { out[OFF_MEM + i] = 0.f; return; }
  int j = i - SZ_MEM;
  if (j < SZ_MASK) {
    int b = j / 24, l = j - b*24;
    out[OFF_MASK + j] = (l >= counts[b]) ? 1.f : 0.f;
  }
}

__global__ __launch_bounds__(256) void scatter_k(const float* __restrict__ rel,
    const int* __restrict__ pos, const int* __restrict__ im, float* __restrict__ out) {
  int n = blockIdx.x;
  int l = pos[n], b = im[n];
  float* dst = out + OFF_MEM + ((size_t)l*16 + b)*1936;
  const float* src = rel + (size_t)n*1936;
  for (int d = threadIdx.x; d < 1936; d += 256) dst[d] = src[d];
}

__global__ __launch_bounds__(256) void pooled_k(const float* __restrict__ rel,
    const int* __restrict__ starts, const int* __restrict__ counts,
    float* __restrict__ out) {
  int b = blockIdx.y;
  int d = blockIdx.x*256 + threadIdx.x;
  if (d >= 1936) return;
  int st = starts[b], ct = counts[b];
  float mx = -INFINITY;
  for (int i = 0; i < ct; i++) mx = fmaxf(mx, rel[(size_t)(st + i)*1936 + d]);
  out[OFF_POOLED + b*1936 + d] = mx;
}

extern "C" void kernel_launch(void* const* d_in, const int* in_sizes, int n_in,
                              void* d_out, int out_size, void* d_ws, size_t ws_size,
                              hipStream_t stream) {
  const float* features   = (const float*)d_in[0];
  const int*   pair_idx   = (const int*)d_in[1];
  const int*   im_idx     = (const int*)d_in[2];
  const int*   labels     = (const int*)d_in[3];
  const float* union_feat = (const float*)d_in[4];
  const float* spatial    = (const float*)d_in[5];
  const float* w_union    = (const float*)d_in[6];
  const float* b_union    = (const float*)d_in[7];
  const float* conv1_w    = (const float*)d_in[8];
  const float* conv1_b    = (const float*)d_in[9];
  const float* bn1_g      = (const float*)d_in[10];
  const float* bn1_b      = (const float*)d_in[11];
  const float* bn1_m      = (const float*)d_in[12];
  const float* bn1_v      = (const float*)d_in[13];
  const float* conv2_w    = (const float*)d_in[14];
  const float* conv2_b    = (const float*)d_in[15];
  const float* bn2_g      = (const float*)d_in[16];
  const float* bn2_b      = (const float*)d_in[17];
  const float* bn2_m      = (const float*)d_in[18];
  const float* bn2_v      = (const float*)d_in[19];
  const float* subj_w     = (const float*)d_in[20];
  const float* subj_b     = (const float*)d_in[21];
  const float* obj_w      = (const float*)d_in[22];
  const float* obj_b      = (const float*)d_in[23];
  const float* vr_w       = (const float*)d_in[24];
  const float* vr_b       = (const float*)d_in[25];
  const float* emb1       = (const float*)d_in[26];
  const float* emb2       = (const float*)d_in[27];
  const float* bil_w      = (const float*)d_in[28];
  const float* bil_b      = (const float*)d_in[29];
  const float* lin_w      = (const float*)d_in[30];
  const float* lin_b      = (const float*)d_in[31];
  const float* proj_w     = (const float*)d_in[32];
  const float* proj_b     = (const float*)d_in[33];
  const float* ac_w       = (const float*)d_in[34];
  const float* ac_b       = (const float*)d_in[35];

  float* ws = (float*)d_ws;
  float* s_mat  = ws + OFF_S;
  float* o_mat  = ws + OFF_O;
  float* z1     = ws + OFF_Z1;
  float* bilbuf = ws + OFF_BIL;
  float* rel    = ws + OFF_REL;
  float* ubuf   = ws + OFF_UBUF;   // layout [n][oc][q] = [256][256][49]
  float* x1     = ws + OFF_X1;
  float* xp     = ws + OFF_XP;
  float* pvr    = ws + OFF_PVR;
  float* pbil   = ws + OFF_PBIL;
  float* plin   = ws + OFF_PLIN;
  float* pproj  = ws + OFF_PPROJ;
  int*   ints   = (int*)(ws + OFF_INTS);
  int* counts = ints; int* starts = ints + 16; int* pos = ints + 32;
  float* out = (float*)d_out;

  dim3 blk(256);

  // subj + obj linears in ONE dispatch (blockIdx.z selects weights/output)
  {
    GP g{}; g.A = features; g.gidx = pair_idx;
    g.B = subj_w;  g.bias = subj_b;  g.C = s_mat;
    g.B2 = obj_w;  g.bias2 = obj_b;  g.C2 = o_mat;
    g.M = 256; g.N = 512; g.K = 2048; g.ldc = 712; g.coff = 0; g.kChunk = 2048;
    gemm_k<0><<<dim3(8,4,2), blk, 0, stream>>>(g);
  }
  // embedding concat -> cols [512,712)
  emb_k<<<dim3(400), blk, 0, stream>>>(pair_idx, labels, emb1, emb2, s_mat, o_mat);

  // union 1x1 conv as GEMM -> ubuf[n][oc][q] (scatter epilogue)
  {
    GP g{}; g.A = union_feat; g.B = w_union; g.bias = b_union; g.C = ubuf;
    g.M = 12544; g.N = 256; g.K = 1024; g.kChunk = 1024;
    gemm_k<5><<<dim3(4,196,1), blk, 0, stream>>>(g);
  }

  // conv1 + relu + bn1 -> x1 ; maxpool -> xp
  conv1_k<<<dim3(1792), blk, 0, stream>>>(spatial, conv1_w, conv1_b,
                                          bn1_g, bn1_b, bn1_m, bn1_v, x1);
  pool_k<<<dim3(6272), blk, 0, stream>>>(x1, xp);

  // conv2 (implicit GEMM) + relu + bn2, accumulated into ubuf[n][oc][q]
  {
    GP g{}; g.A = xp; g.B = conv2_w; g.bias = conv2_b; g.C = ubuf;
    g.M = 12544; g.N = 256; g.K = 1152; g.kChunk = 1152;
    g.bn_g = bn2_g; g.bn_b = bn2_b; g.bn_m = bn2_m; g.bn_v = bn2_v;
    gemm_k<6><<<dim3(4,196,1), blk, 0, stream>>>(g);
  }

  // vr linear: split-K 32 -> partials -> rel[:,1424:1936]
  {
    GP g{}; g.A = ubuf; g.B = vr_w; g.C = pvr;
    g.M = 256; g.N = 512; g.K = 12544; g.kChunk = 392;
    gemm_k<2><<<dim3(8,4,32), blk, 0, stream>>>(g);
    reduce_k<<<dim3(512), blk, 0, stream>>>(pvr, vr_b, rel, 32, 256*512, 512, 1936, 1424);
  }

  // lin: concat(s,o) @ lin_w^T, split-K 4 -> partials -> z1
  {
    GP g{}; g.A = s_mat; g.A2 = o_mat; g.B = lin_w; g.C = plin;
    g.M = 256; g.N = 712; g.K = 1424; g.kChunk = 356;
    gemm_k<3><<<dim3(12,4,4), blk, 0, stream>>>(g);
    reduce_k<<<dim3(712), blk, 0, stream>>>(plin, lin_b, z1, 4, 256*712, 712, 712, 0);
  }

  // bilinear: single-bf16 MFMA, lgkm-only barriers, split-K 61 -> bilbuf
  bil_mfma_k<<<dim3(12, 2, BILSPLIT), dim3(256), 0, stream>>>(s_mat, o_mat, bil_w, pbil);
  reduce_k<<<dim3(712), blk, 0, stream>>>(pbil, bil_b, bilbuf, BILSPLIT, 256*712, 712, 712, 0);

  // proj: relu(concat(z1,bil)) @ proj_w^T, split-K 2 -> partials -> rel[:,0:1424]
  {
    GP g{}; g.A = z1; g.A2 = bilbuf; g.B = proj_w; g.C = pproj;
    g.M = 256; g.N = 1424; g.K = 1424; g.kChunk = 712;
    gemm_k<4><<<dim3(23,4,2), blk, 0, stream>>>(g);
    reduce_k<<<dim3(1424), blk, 0, stream>>>(pproj, proj_b, rel, 2, 256*1424, 1424, 1936, 0);
  }

  // segments, memory zero + mask, scatter, pooled max
  seg_k<<<dim3(1), blk, 0, stream>>>(im_idx, counts, starts, pos);
  zeromask_k<<<dim3((SZ_MEM + SZ_MASK + 255)/256), blk, 0, stream>>>(out, counts);
  scatter_k<<<dim3(256), blk, 0, stream>>>(rel, pos, im_idx, out);
  pooled_k<<<dim3(8,16), blk, 0, stream>>>(rel, starts, counts, out);

  // act = sigmoid(pooled @ ac_w^T + ac_b)
  {
    GP g{}; g.A = out + OFF_POOLED; g.B = ac_w; g.bias = ac_b; g.C = out + OFF_ACT;
    g.M = 16; g.N = 157; g.K = 1936; g.ldc = 157; g.coff = 0; g.kChunk = 1936;
    gemm_k<8><<<dim3(3,1,1), blk, 0, stream>>>(g);
  }
}